// Round 14
// baseline (230.227 us; speedup 1.0000x reference)
//
#include <hip/hip_runtime.h>
#include <cstdint>

typedef unsigned short u16;
typedef short s8v __attribute__((ext_vector_type(8)));
typedef float f4v __attribute__((ext_vector_type(4)));

// fp32 -> bf16 round-to-nearest-even (bit trick)
__device__ __forceinline__ u16 f2b(float f) {
  uint32_t u = __float_as_uint(f);
  u = (u + 0x7FFFu + ((u >> 16) & 1u)) >> 16;
  return (u16)u;
}

// pack two f32 -> bf16x2 (RNE) in one instruction (T12 recipe; no builtin)
__device__ __forceinline__ uint32_t pk2(float a, float b) {
  uint32_t r;
  asm("v_cvt_pk_bf16_f32 %0, %1, %2" : "=v"(r) : "v"(a), "v"(b));
  return r;
}

// async global->LDS, 16B per lane (wave-uniform LDS base + lane*16 layout)
__device__ __forceinline__ void gload16(const u16* g, u16* l) {
  __builtin_amdgcn_global_load_lds(
      (const __attribute__((address_space(1))) void*)g,
      (__attribute__((address_space(3))) void*)l, 16, 0, 0);
}

// ---------------------------------------------------------------------------
// Fused prep kernel
// blocks: [0,4096) conv_x | [4096,4864) convT_w | [4864,5120) convT_wo |
//         [5120,5136) conv_bias
// ---------------------------------------------------------------------------
__global__ void prep(const float* __restrict__ x, u16* __restrict__ xb,
                     const float* __restrict__ WQ, const float* __restrict__ WK,
                     const float* __restrict__ WV, const float* __restrict__ WO,
                     u16* __restrict__ WTqkv, u16* __restrict__ WOT,
                     const float* __restrict__ bQ, const float* __restrict__ bK,
                     const float* __restrict__ bV, const float* __restrict__ bO,
                     float* __restrict__ bqkv, float* __restrict__ bsum) {
  __shared__ u16 tile[64][65];
  const int bid = blockIdx.x;
  const int tid = threadIdx.x;

  if (bid < 4096) {                       // x fp32 -> bf16, 4 elems/thread
    int i = bid * 256 + tid;
    float4 v = ((const float4*)x)[i];
    uint2 o;
    o.x = (uint32_t)f2b(v.x) | ((uint32_t)f2b(v.y) << 16);
    o.y = (uint32_t)f2b(v.z) | ((uint32_t)f2b(v.w) << 16);
    ((uint2*)xb)[i] = o;
  } else if (bid < 4864) {                // W_{Q,K,V} -> WTqkv (B^T), 64x64 transpose
    int sub = bid - 4096;
    int w = sub >> 8, sub2 = sub & 255;
    const float* W = (w == 0) ? WQ : (w == 1) ? WK : WV;
    u16* dst = WTqkv + (size_t)w * 1024 * 1024;
    const int m0 = (sub2 & 15) * 64;
    const int h  = sub2 >> 4;
    const int c  = tid & 63;
    const int r4 = tid >> 6;
    const float* Wh = W + (size_t)h * 65536;
    for (int i = 0; i < 16; ++i) {
      int lm = i * 4 + r4;
      tile[lm][c] = f2b(Wh[(size_t)(m0 + lm) * 64 + c]);
    }
    __syncthreads();
    for (int i = 0; i < 16; ++i) {
      int dd = i * 4 + r4;
      dst[((size_t)h * 64 + dd) * 1024 + m0 + c] = tile[c][dd];
    }
  } else if (bid < 5120) {                // W_O flat [1024][1024] -> WOT[m][k]
    int sub = bid - 4864;
    const int k0 = (sub & 15) * 64;
    const int m0 = (sub >> 4) * 64;
    const int c  = tid & 63;
    const int r4 = tid >> 6;
    for (int i = 0; i < 16; ++i) {
      int lk = i * 4 + r4;
      tile[lk][c] = f2b(WO[(size_t)(k0 + lk) * 1024 + m0 + c]);
    }
    __syncthreads();
    for (int i = 0; i < 16; ++i) {
      int lm = i * 4 + r4;
      WOT[(size_t)(m0 + lm) * 1024 + k0 + c] = tile[c][lm];
    }
  } else {                                // biases
    int t = (bid - 5120) * 256 + tid;
    if (t < 1024)       bqkv[t] = bQ[t];
    else if (t < 2048)  bqkv[t] = bK[t - 1024];
    else if (t < 3072)  bqkv[t] = bV[t - 2048];
    else {
      int m = t - 3072;
      float s = 0.f;
      for (int hh = 0; hh < 16; ++hh) s += bO[hh * 1024 + m];
      bsum[m] = s;
    }
  }
}

// ---------------------------------------------------------------------------
// bf16 MFMA GEMM: C = (A * BT^T + bias[col]) * (col<scale_cols ? 0.125 : 1)
// BMxBN tile, BK in {32,64}, NTHR/64 waves, per-wave 64x(BN/2). BK=64 staged
// as two BK=32 half-tiles (wave-uniform-dest rule preserved). 2-phase
// pipeline: STAGE(next) before ds_read+MFMA of current, one barrier/K-step.
// FUSE_VT (QKV proj): blocks with n0 >= 2048 emit V columns TRANSPOSED to
// VTout[(h*64+d)][token] via an LDS bounce (stride 136).
// ---------------------------------------------------------------------------
template<bool OUT_F32, int BM, int BN, int NTHR, bool FUSE_VT, int BK>
__global__ void gemm_bt(const u16* __restrict__ A, const u16* __restrict__ BT,
                        const float* __restrict__ bias, void* __restrict__ Cout,
                        u16* __restrict__ VTout, int N, int K, int scale_cols) {
  constexpr int NW = NTHR / 64;
  constexpr int WM = NW / 2;
  constexpr int NJ = BN / 32;
  constexpr int NH = BK / 32;            // half-tiles per K-step
  constexpr int ASEG = BM * 4 / NTHR;
  constexpr int BSEG = BN * 4 / NTHR;
  constexpr int STG_U16 = 2 * NH * (BM + BN) * 32;
  constexpr int CT_STRIDE = BM + 8;
  constexpr int SMEM_U16 = (FUSE_VT && BN * CT_STRIDE > STG_U16)
                               ? BN * CT_STRIDE : STG_U16;
  static_assert(BM / WM == 64, "per-wave rows must be 64");
  static_assert(BM * 4 % NTHR == 0 && BN * 4 % NTHR == 0, "staging divisibility");

  __shared__ __align__(16) u16 smem[SMEM_U16];
  u16* sA = smem;                        // [2][NH][BM*32]
  u16* sB = smem + 2 * NH * BM * 32;     // [2][NH][BN*32]

  const int tid  = threadIdx.x;
  const int lane = tid & 63, wave = tid >> 6;
  const int wm = wave >> 1, wn = wave & 1;
  const int lq = lane & 15, quad = lane >> 4;
  const int m0 = blockIdx.y * BM, n0 = blockIdx.x * BN;

  f4v acc[4][NJ] = {};

  auto STAGE = [&](int buf, int k0) {
    for (int hh = 0; hh < NH; ++hh) {
      for (int i = 0; i < ASEG; ++i) {
        int s = tid + i * NTHR;
        int row = s >> 2, part = s & 3;
        gload16(A + (size_t)(m0 + row) * K + k0 + hh * 32 + part * 8,
                &sA[(buf * NH + hh) * BM * 32 + s * 8]);
      }
      for (int i = 0; i < BSEG; ++i) {
        int s = tid + i * NTHR;
        int row = s >> 2, part = s & 3;
        gload16(BT + (size_t)(n0 + row) * K + k0 + hh * 32 + part * 8,
                &sB[(buf * NH + hh) * BN * 32 + s * 8]);
      }
    }
  };

  STAGE(0, 0);
  __syncthreads();                       // compiler drains vmcnt before barrier
  int cur = 0;
  for (int k0 = 0; k0 < K; k0 += BK) {
    if (k0 + BK < K) STAGE(cur ^ 1, k0 + BK);   // issue next-tile loads FIRST
    for (int hh = 0; hh < NH; ++hh) {
      s8v af[4], bfr[NJ];
      for (int i = 0; i < 4; ++i)
        af[i]  = *(const s8v*)&sA[(cur * NH + hh) * BM * 32 +
                                  (wm * 64 + i * 16 + lq) * 32 + quad * 8];
      for (int j = 0; j < NJ; ++j)
        bfr[j] = *(const s8v*)&sB[(cur * NH + hh) * BN * 32 +
                                  (wn * (BN / 2) + j * 16 + lq) * 32 + quad * 8];
      for (int i = 0; i < 4; ++i)
        for (int j = 0; j < NJ; ++j)
          acc[i][j] = __builtin_amdgcn_mfma_f32_16x16x32_bf16(af[i], bfr[j], acc[i][j], 0, 0, 0);
    }
    __syncthreads();                     // next-tile loads overlapped the MFMAs
    cur ^= 1;
  }

  if (FUSE_VT && n0 >= 2048) {
    const int vcol0 = n0 - 2048;
    u16* ct = smem;                      // staging LDS dead past final barrier
    for (int i = 0; i < 4; ++i)
      for (int j = 0; j < NJ; ++j) {
        int row = wm * 64 + i * 16 + quad * 4;
        int col = wn * (BN / 2) + j * 16 + lq;
        float bb = bias[n0 + col];       // V cols: no 0.125 scale
        uint2 w;
        w.x = pk2(acc[i][j][0] + bb, acc[i][j][1] + bb);
        w.y = pk2(acc[i][j][2] + bb, acc[i][j][3] + bb);
        *(uint2*)&ct[col * CT_STRIDE + row] = w;
      }
    __syncthreads();
    if (tid < BN * 2) {
      int cc = tid >> 1, half = tid & 1;
      const uint4* src = (const uint4*)&ct[cc * CT_STRIDE + half * (BM / 2)];
      uint4* dst = (uint4*)&VTout[(size_t)(vcol0 + cc) * 4096 + m0 + half * (BM / 2)];
#pragma unroll
      for (int k = 0; k < BM / 16; ++k) dst[k] = src[k];
    }
    return;
  }

  for (int i = 0; i < 4; ++i)
    for (int j = 0; j < NJ; ++j) {
      int row = m0 + wm * 64 + i * 16 + quad * 4;
      int col = n0 + wn * (BN / 2) + j * 16 + lq;
      float bb = bias[col];
      float sc = (col < scale_cols) ? 0.125f : 1.0f;
      for (int r = 0; r < 4; ++r) {
        float v = (acc[i][j][r] + bb) * sc;
        if (OUT_F32) ((float*)Cout)[(size_t)(row + r) * N + col] = v;
        else         ((u16*)Cout)[(size_t)(row + r) * N + col] = f2b(v);
      }
    }
}

// ---------------------------------------------------------------------------
// Flash attention (causal). 1 wave handles FOUR adjacent 16-query tiles
// (rows q0..q0+63, tiles 4v..4v+3 share nchunk and K/V). KVBLK=32.
// Round-14: 4 independent chains/wave (was 2), K/V loaded once per chunk for
// all 4 tiles (load-issue per unit work halved again). Grid 1024 = 4/CU.
// KVBLK=32 (not 64) keeps kf+vf at 32 VGPR -> est. total <200, no spill.
// Heavy+light v pairing; per-chunk math identical to the proven rounds
// (swapped QK^T, scalar softmax state, packed P, ping-pong P LDS + fences,
// defer-max, setprio). Masking: only chunks c >= nchunk-2 can cross the
// diagonal of the 64-row band (fully-masked tile-chunks give p=0 exactly).
// ---------------------------------------------------------------------------
__global__ __launch_bounds__(64, 2) void attn_fwd(const u16* __restrict__ QKV,
                                                  const u16* __restrict__ VT,
                                                  u16* __restrict__ Z) {
  __shared__ __align__(16) u16 sP[4][2][16 * 40];   // [tile][pingpong], 16x32 P
  const int lane = threadIdx.x;
  const int lq = lane & 15, quad = lane >> 4;

  const int id   = blockIdx.x;             // 0..1023
  const int xcd  = id & 7;
  const int slot = id >> 3;                // 0..127 per XCD
  const int cwx  = slot >> 5;              // combo-within-XCD 0..3
  const int s    = slot & 31;
  const int v    = (s < 16) ? (31 - s) : (s - 16);  // heavy+light pairing
  const int g    = xcd + 8 * cwx;
  const int h = g & 15, b = g >> 4;
  const int q0 = v * 64;                   // rows q0 .. q0+63
  const int nchunk = 2 * v + 2;            // 32-key chunks

  const int RS = 3072;
  const u16* base = QKV + (size_t)b * 2048 * RS;
  const u16* Qb  = base + h * 64;
  const u16* Kb  = base + 1024 + h * 64;
  const u16* VTb = VT + (size_t)h * 64 * 4096 + (size_t)b * 2048;

  // Q frags (B-operand): tile t, lane holds Q[q0+16t+lq][d=32*j+quad*8..]
  s8v qf[4][2];
#pragma unroll
  for (int t = 0; t < 4; ++t) {
    qf[t][0] = *(const s8v*)&Qb[(size_t)(q0 + 16 * t + lq) * RS + quad * 8];
    qf[t][1] = *(const s8v*)&Qb[(size_t)(q0 + 16 * t + lq) * RS + 32 + quad * 8];
  }

  f4v z[4][4] = {};                     // [tile][dc]: Z[q=quad*4+r][d=dc*16+lq]
  float mrow[4], lsum[4];
#pragma unroll
  for (int t = 0; t < 4; ++t) { mrow[t] = -3.0e38f; lsum[t] = 0.f; }

  s8v kf[4], vf[4];   // single buffers for the current chunk (32 keys)

#define LOADK(c_) do {                                                        \
    const int kk0_ = (c_) * 32;                                               \
    const u16* kr0_ = &Kb[(size_t)(kk0_ + lq) * RS + quad * 8];               \
    const u16* kr1_ = &Kb[(size_t)(kk0_ + 16 + lq) * RS + quad * 8];          \
    kf[0] = *(const s8v*)kr0_;                                                \
    kf[1] = *(const s8v*)(kr0_ + 32);                                         \
    kf[2] = *(const s8v*)kr1_;                                                \
    kf[3] = *(const s8v*)(kr1_ + 32);                                         \
  } while (0)

#define LOADV(c_) do {                                                        \
    const int kk0_ = (c_) * 32;                                               \
    _Pragma("unroll")                                                         \
    for (int d_ = 0; d_ < 4; ++d_)                                            \
      vf[d_] = *(const s8v*)&VTb[(size_t)(d_ * 16 + lq) * 4096 + kk0_ + quad * 8]; \
  } while (0)

  // softmax of 32-key chunk c for tile t (swapped layout) + packed P write
  auto SMW = [&](int c, int t, f4v sacc0, f4v sacc1) {
    float s0[4], s1[4];
    for (int r = 0; r < 4; ++r) { s0[r] = sacc0[r]; s1[r] = sacc1[r]; }
    if (c >= nchunk - 2) {              // only last 2 chunks can cross diag
      const int kb = c * 32, qt0 = q0 + 16 * t;
      for (int r = 0; r < 4; ++r) {
        if (kb + quad * 4 + r > qt0 + lq)      s0[r] = -3.0e38f;
        if (kb + 16 + quad * 4 + r > qt0 + lq) s1[r] = -3.0e38f;
      }
    }
    float lmax = fmaxf(fmaxf(fmaxf(s0[0], s0[1]), fmaxf(s0[2], s0[3])),
                       fmaxf(fmaxf(s1[0], s1[1]), fmaxf(s1[2], s1[3])));
    if (!__all(lmax <= mrow[t] + 8.0f)) {   // defer-max, THR=8
      float tt = lmax;
      tt = fmaxf(tt, __shfl_xor(tt, 16, 64));
      tt = fmaxf(tt, __shfl_xor(tt, 32, 64));
      float mnew = fmaxf(mrow[t], tt);
      float al = __expf(mrow[t] - mnew);
      mrow[t] = mnew;
      lsum[t] *= al;
      float alr[4];
      for (int r = 0; r < 4; ++r) alr[r] = __shfl(al, quad * 4 + r, 16);
      for (int dc = 0; dc < 4; ++dc)
        for (int r = 0; r < 4; ++r) z[t][dc][r] *= alr[r];
    }
    float p0[4], p1[4], acc = 0.f;
    for (int r = 0; r < 4; ++r) {
      p0[r] = __expf(s0[r] - mrow[t]);
      p1[r] = __expf(s1[r] - mrow[t]);
      acc += p0[r] + p1[r];
    }
    lsum[t] += acc;
    uint2 wlo, whi;
    wlo.x = pk2(p0[0], p0[1]); wlo.y = pk2(p0[2], p0[3]);
    whi.x = pk2(p1[0], p1[1]); whi.y = pk2(p1[2], p1[3]);
    u16* rowp = &sP[t][c & 1][lq * 40 + quad * 4];
    *(uint2*)rowp        = wlo;         // ds_write_b64, k = quad*4..+3
    *(uint2*)(rowp + 16) = whi;         // ds_write_b64, k = 16+quad*4..+3
  };

#define QK(a0_, a1_) do {                                                     \
    _Pragma("unroll")                                                         \
    for (int t_ = 0; t_ < 4; ++t_) {                                          \
      a0_[t_] = __builtin_amdgcn_mfma_f32_16x16x32_bf16(kf[0], qf[t_][0], a0_[t_], 0, 0, 0); \
      a0_[t_] = __builtin_amdgcn_mfma_f32_16x16x32_bf16(kf[1], qf[t_][1], a0_[t_], 0, 0, 0); \
      a1_[t_] = __builtin_amdgcn_mfma_f32_16x16x32_bf16(kf[2], qf[t_][0], a1_[t_], 0, 0, 0); \
      a1_[t_] = __builtin_amdgcn_mfma_f32_16x16x32_bf16(kf[3], qf[t_][1], a1_[t_], 0, 0, 0); \
    }                                                                         \
  } while (0)

  // PV from ping-pong buffer pb (P of the previous chunk) + current vf
  auto PV = [&](int pb) {
#pragma unroll
    for (int t = 0; t < 4; ++t) {
      s8v pf = *(const s8v*)&sP[t][pb][lq * 40 + quad * 8];
#pragma unroll
      for (int dc = 0; dc < 4; ++dc)
        z[t][dc] = __builtin_amdgcn_mfma_f32_16x16x32_bf16(pf, vf[dc], z[t][dc], 0, 0, 0);
    }
  };

  LOADK(0);
  { // chunk 0: QK + softmax + P write into buf 0 (PV deferred)
    f4v a0[4] = {}, a1[4] = {};
    __builtin_amdgcn_s_setprio(1);
    QK(a0, a1);
    __builtin_amdgcn_s_setprio(0);
    LOADK(1);                           // nchunk >= 2 always
    LOADV(0);
#pragma unroll
    for (int t = 0; t < 4; ++t) SMW(0, t, a0[t], a1[t]);
    asm volatile("" ::: "memory");      // P(0) writes pinned before PV reads
  }

  for (int c = 1; c < nchunk; ++c) {
    f4v a0[4] = {}, a1[4] = {};
    __builtin_amdgcn_s_setprio(1);
    QK(a0, a1);                         // kf = K(c)
    PV((c + 1) & 1);                    // reads P(c-1) + vf = V(c-1)
    __builtin_amdgcn_s_setprio(0);
    asm volatile("" ::: "memory");      // PV reads pinned before SMW writes
    if (c + 1 < nchunk) LOADK(c + 1);   // safe: QK consumed kf at issue
    LOADV(c);                           // safe: PV consumed vf at issue
#pragma unroll
    for (int t = 0; t < 4; ++t) SMW(c, t, a0[t], a1[t]);
    asm volatile("" ::: "memory");      // P(c) writes pinned before next PV
  }

  { // drain: PV(nchunk-1) from the last-written buffer
    __builtin_amdgcn_s_setprio(1);
    PV((nchunk - 1) & 1);
    __builtin_amdgcn_s_setprio(0);
  }
#undef QK
#undef LOADK
#undef LOADV

  // one-time sum reduction across the 4 quad-lanes of each row
#pragma unroll
  for (int t = 0; t < 4; ++t) {
    lsum[t] += __shfl_xor(lsum[t], 16, 64);
    lsum[t] += __shfl_xor(lsum[t], 32, 64);
  }
#pragma unroll
  for (int t = 0; t < 4; ++t) {
    float inv[4];
    for (int r = 0; r < 4; ++r)
      inv[r] = 1.0f / __shfl(lsum[t], quad * 4 + r, 16);
    for (int dc = 0; dc < 4; ++dc)
      for (int r = 0; r < 4; ++r) {
        size_t row = (size_t)b * 2048 + q0 + 16 * t + quad * 4 + r;
        Z[row * 1024 + h * 64 + dc * 16 + lq] = f2b(z[t][dc][r] * inv[r]);
      }
  }
}

// ---------------------------------------------------------------------------
// Launch
// ---------------------------------------------------------------------------
extern "C" void kernel_launch(void* const* d_in, const int* in_sizes, int n_in,
                              void* d_out, int out_size, void* d_ws, size_t ws_size,
                              hipStream_t stream) {
  const float* x  = (const float*)d_in[0];
  const float* WQ = (const float*)d_in[1];
  const float* bQ = (const float*)d_in[2];
  const float* WK = (const float*)d_in[3];
  const float* bK = (const float*)d_in[4];
  const float* WV = (const float*)d_in[5];
  const float* WO = (const float*)d_in[6];
  const float* bV = (const float*)d_in[7];
  const float* bO = (const float*)d_in[8];
  float* out = (float*)d_out;

  uint8_t* ws = (uint8_t*)d_ws;
  u16*   xb    = (u16*)(ws);                       //  8 MB  [4096][1024] bf16 x
  u16*   WTqkv = (u16*)(ws + 8388608);             //  6 MB
  u16*   WOT   = (u16*)(ws + 14680064);            //  2 MB
  u16*   QKV   = (u16*)(ws + 16777216);            // 24 MB (V third unused)
  u16*   Zb    = (u16*)(ws + 41943040);            //  8 MB
  float* bqkv  = (float*)(ws + 50331648);          // 12 KB
  float* bsum  = (float*)(ws + 50343936);          //  4 KB
  u16*   VTv   = (u16*)(ws + 50348032);            //  8 MB V^T (own region)

  // fused prep: conv_x + 3x convT_w + convT_wo + conv_bias
  prep<<<5136, 256, 0, stream>>>(x, xb, WQ, WK, WV, WO, WTqkv, WOT,
                                 bQ, bK, bV, bO, bqkv, bsum);
  // QKV projection (Q cols pre-scaled by 0.125), fused V-transpose epilogue:
  // 128x128 tile, BK=32, 768 blocks = exactly 3/CU
  gemm_bt<false, 128, 128, 256, true, 32><<<dim3(24, 32), 256, 0, stream>>>(
      xb, WTqkv, bqkv, (void*)QKV, VTv, 3072, 1024, 1024);
  // attention: 1024 one-wave blocks, 4 q-tiles each, heavy+light on v
  attn_fwd<<<dim3(1024, 1, 1), 64, 0, stream>>>(QKV, VTv, Zb);
  // output projection: 128x64 tile, BK=64 (2 half-stages), 512 blocks = 2/CU
  gemm_bt<true, 128, 64, 256, false, 64><<<dim3(16, 32), 256, 0, stream>>>(
      Zb, WOT, bsum, (void*)out, nullptr, 1024, 1024, 0);
}

// Round 15
// 208.828 us; speedup vs baseline: 1.1025x; 1.1025x over previous
//
#include <hip/hip_runtime.h>
#include <cstdint>

typedef unsigned short u16;
typedef short s8v __attribute__((ext_vector_type(8)));
typedef float f4v __attribute__((ext_vector_type(4)));

// fp32 -> bf16 round-to-nearest-even (bit trick)
__device__ __forceinline__ u16 f2b(float f) {
  uint32_t u = __float_as_uint(f);
  u = (u + 0x7FFFu + ((u >> 16) & 1u)) >> 16;
  return (u16)u;
}

// pack two f32 -> bf16x2 (RNE) in one instruction (T12 recipe; no builtin)
__device__ __forceinline__ uint32_t pk2(float a, float b) {
  uint32_t r;
  asm("v_cvt_pk_bf16_f32 %0, %1, %2" : "=v"(r) : "v"(a), "v"(b));
  return r;
}

// async global->LDS, 16B per lane (wave-uniform LDS base + lane*16 layout)
__device__ __forceinline__ void gload16(const u16* g, u16* l) {
  __builtin_amdgcn_global_load_lds(
      (const __attribute__((address_space(1))) void*)g,
      (__attribute__((address_space(3))) void*)l, 16, 0, 0);
}

// ---------------------------------------------------------------------------
// Fused prep kernel
// blocks: [0,4096) conv_x | [4096,4864) convT_w | [4864,5120) convT_wo |
//         [5120,5136) conv_bias
// ---------------------------------------------------------------------------
__global__ void prep(const float* __restrict__ x, u16* __restrict__ xb,
                     const float* __restrict__ WQ, const float* __restrict__ WK,
                     const float* __restrict__ WV, const float* __restrict__ WO,
                     u16* __restrict__ WTqkv, u16* __restrict__ WOT,
                     const float* __restrict__ bQ, const float* __restrict__ bK,
                     const float* __restrict__ bV, const float* __restrict__ bO,
                     float* __restrict__ bqkv, float* __restrict__ bsum) {
  __shared__ u16 tile[64][65];
  const int bid = blockIdx.x;
  const int tid = threadIdx.x;

  if (bid < 4096) {                       // x fp32 -> bf16, 4 elems/thread
    int i = bid * 256 + tid;
    float4 v = ((const float4*)x)[i];
    uint2 o;
    o.x = (uint32_t)f2b(v.x) | ((uint32_t)f2b(v.y) << 16);
    o.y = (uint32_t)f2b(v.z) | ((uint32_t)f2b(v.w) << 16);
    ((uint2*)xb)[i] = o;
  } else if (bid < 4864) {                // W_{Q,K,V} -> WTqkv (B^T), 64x64 transpose
    int sub = bid - 4096;
    int w = sub >> 8, sub2 = sub & 255;
    const float* W = (w == 0) ? WQ : (w == 1) ? WK : WV;
    u16* dst = WTqkv + (size_t)w * 1024 * 1024;
    const int m0 = (sub2 & 15) * 64;
    const int h  = sub2 >> 4;
    const int c  = tid & 63;
    const int r4 = tid >> 6;
    const float* Wh = W + (size_t)h * 65536;
    for (int i = 0; i < 16; ++i) {
      int lm = i * 4 + r4;
      tile[lm][c] = f2b(Wh[(size_t)(m0 + lm) * 64 + c]);
    }
    __syncthreads();
    for (int i = 0; i < 16; ++i) {
      int dd = i * 4 + r4;
      dst[((size_t)h * 64 + dd) * 1024 + m0 + c] = tile[c][dd];
    }
  } else if (bid < 5120) {                // W_O flat [1024][1024] -> WOT[m][k]
    int sub = bid - 4864;
    const int k0 = (sub & 15) * 64;
    const int m0 = (sub >> 4) * 64;
    const int c  = tid & 63;
    const int r4 = tid >> 6;
    for (int i = 0; i < 16; ++i) {
      int lk = i * 4 + r4;
      tile[lk][c] = f2b(WO[(size_t)(k0 + lk) * 1024 + m0 + c]);
    }
    __syncthreads();
    for (int i = 0; i < 16; ++i) {
      int lm = i * 4 + r4;
      WOT[(size_t)(m0 + lm) * 1024 + k0 + c] = tile[c][lm];
    }
  } else {                                // biases
    int t = (bid - 5120) * 256 + tid;
    if (t < 1024)       bqkv[t] = bQ[t];
    else if (t < 2048)  bqkv[t] = bK[t - 1024];
    else if (t < 3072)  bqkv[t] = bV[t - 2048];
    else {
      int m = t - 3072;
      float s = 0.f;
      for (int hh = 0; hh < 16; ++hh) s += bO[hh * 1024 + m];
      bsum[m] = s;
    }
  }
}

// ---------------------------------------------------------------------------
// bf16 MFMA GEMM: C = (A * BT^T + bias[col]) * (col<scale_cols ? 0.125 : 1)
// BMxBN tile, BK in {32,64}, NTHR/64 waves, per-wave 64x(BN/2). BK=64 staged
// as two BK=32 half-tiles (wave-uniform-dest rule preserved). 2-phase
// pipeline: STAGE(next) before ds_read+MFMA of current, one barrier/K-step.
// FUSE_VT (QKV proj): blocks with n0 >= 2048 emit V columns TRANSPOSED to
// VTout[(h*64+d)][token] via an LDS bounce (stride 136).
// ---------------------------------------------------------------------------
template<bool OUT_F32, int BM, int BN, int NTHR, bool FUSE_VT, int BK>
__global__ void gemm_bt(const u16* __restrict__ A, const u16* __restrict__ BT,
                        const float* __restrict__ bias, void* __restrict__ Cout,
                        u16* __restrict__ VTout, int N, int K, int scale_cols) {
  constexpr int NW = NTHR / 64;
  constexpr int WM = NW / 2;
  constexpr int NJ = BN / 32;
  constexpr int NH = BK / 32;            // half-tiles per K-step
  constexpr int ASEG = BM * 4 / NTHR;
  constexpr int BSEG = BN * 4 / NTHR;
  constexpr int STG_U16 = 2 * NH * (BM + BN) * 32;
  constexpr int CT_STRIDE = BM + 8;
  constexpr int SMEM_U16 = (FUSE_VT && BN * CT_STRIDE > STG_U16)
                               ? BN * CT_STRIDE : STG_U16;
  static_assert(BM / WM == 64, "per-wave rows must be 64");
  static_assert(BM * 4 % NTHR == 0 && BN * 4 % NTHR == 0, "staging divisibility");

  __shared__ __align__(16) u16 smem[SMEM_U16];
  u16* sA = smem;                        // [2][NH][BM*32]
  u16* sB = smem + 2 * NH * BM * 32;     // [2][NH][BN*32]

  const int tid  = threadIdx.x;
  const int lane = tid & 63, wave = tid >> 6;
  const int wm = wave >> 1, wn = wave & 1;
  const int lq = lane & 15, quad = lane >> 4;
  const int m0 = blockIdx.y * BM, n0 = blockIdx.x * BN;

  f4v acc[4][NJ] = {};

  auto STAGE = [&](int buf, int k0) {
    for (int hh = 0; hh < NH; ++hh) {
      for (int i = 0; i < ASEG; ++i) {
        int s = tid + i * NTHR;
        int row = s >> 2, part = s & 3;
        gload16(A + (size_t)(m0 + row) * K + k0 + hh * 32 + part * 8,
                &sA[(buf * NH + hh) * BM * 32 + s * 8]);
      }
      for (int i = 0; i < BSEG; ++i) {
        int s = tid + i * NTHR;
        int row = s >> 2, part = s & 3;
        gload16(BT + (size_t)(n0 + row) * K + k0 + hh * 32 + part * 8,
                &sB[(buf * NH + hh) * BN * 32 + s * 8]);
      }
    }
  };

  STAGE(0, 0);
  __syncthreads();                       // compiler drains vmcnt before barrier
  int cur = 0;
  for (int k0 = 0; k0 < K; k0 += BK) {
    if (k0 + BK < K) STAGE(cur ^ 1, k0 + BK);   // issue next-tile loads FIRST
    for (int hh = 0; hh < NH; ++hh) {
      s8v af[4], bfr[NJ];
      for (int i = 0; i < 4; ++i)
        af[i]  = *(const s8v*)&sA[(cur * NH + hh) * BM * 32 +
                                  (wm * 64 + i * 16 + lq) * 32 + quad * 8];
      for (int j = 0; j < NJ; ++j)
        bfr[j] = *(const s8v*)&sB[(cur * NH + hh) * BN * 32 +
                                  (wn * (BN / 2) + j * 16 + lq) * 32 + quad * 8];
      for (int i = 0; i < 4; ++i)
        for (int j = 0; j < NJ; ++j)
          acc[i][j] = __builtin_amdgcn_mfma_f32_16x16x32_bf16(af[i], bfr[j], acc[i][j], 0, 0, 0);
    }
    __syncthreads();                     // next-tile loads overlapped the MFMAs
    cur ^= 1;
  }

  if (FUSE_VT && n0 >= 2048) {
    const int vcol0 = n0 - 2048;
    u16* ct = smem;                      // staging LDS dead past final barrier
    for (int i = 0; i < 4; ++i)
      for (int j = 0; j < NJ; ++j) {
        int row = wm * 64 + i * 16 + quad * 4;
        int col = wn * (BN / 2) + j * 16 + lq;
        float bb = bias[n0 + col];       // V cols: no 0.125 scale
        uint2 w;
        w.x = pk2(acc[i][j][0] + bb, acc[i][j][1] + bb);
        w.y = pk2(acc[i][j][2] + bb, acc[i][j][3] + bb);
        *(uint2*)&ct[col * CT_STRIDE + row] = w;
      }
    __syncthreads();
    if (tid < BN * 2) {
      int cc = tid >> 1, half = tid & 1;
      const uint4* src = (const uint4*)&ct[cc * CT_STRIDE + half * (BM / 2)];
      uint4* dst = (uint4*)&VTout[(size_t)(vcol0 + cc) * 4096 + m0 + half * (BM / 2)];
#pragma unroll
      for (int k = 0; k < BM / 16; ++k) dst[k] = src[k];
    }
    return;
  }

  for (int i = 0; i < 4; ++i)
    for (int j = 0; j < NJ; ++j) {
      int row = m0 + wm * 64 + i * 16 + quad * 4;
      int col = n0 + wn * (BN / 2) + j * 16 + lq;
      float bb = bias[col];
      float sc = (col < scale_cols) ? 0.125f : 1.0f;
      for (int r = 0; r < 4; ++r) {
        float v = (acc[i][j][r] + bb) * sc;
        if (OUT_F32) ((float*)Cout)[(size_t)(row + r) * N + col] = v;
        else         ((u16*)Cout)[(size_t)(row + r) * N + col] = f2b(v);
      }
    }
}

// ---------------------------------------------------------------------------
// Flash attention (causal). 1 wave, 2 adjacent 16-query tiles, KVBLK=64.
// Round-13 proven config (attn 71us). Tiles/wave axis fully measured:
// 1 tile=160us, 2 tiles=71us, 4 tiles=101us (round-14: grid 1024 -> 1
// wave/SIMD, occupancy 5.3% -- ILP didn't compensate lost TLP). 2048 blocks
// = 2 waves/SIMD is the interior optimum. Heavy+light CU pairing, single
// K/V register buffers reloaded after MFMA consumption, ping-pong P LDS
// with compiler fences, setprio around MFMA clusters.
// ---------------------------------------------------------------------------
__global__ __launch_bounds__(64, 2) void attn_fwd(const u16* __restrict__ QKV,
                                                  const u16* __restrict__ VT,
                                                  u16* __restrict__ Z) {
  __shared__ __align__(16) u16 sP[2][2][16 * 72];   // [tile][pingpong]
  const int lane = threadIdx.x;
  const int lq = lane & 15, quad = lane >> 4;

  const int id   = blockIdx.x;             // 0..2047
  const int xcd  = id & 7;
  const int slot = id >> 3;                // 0..255 per XCD
  const int g    = xcd + 8 * (slot >> 6);  // combo 0..31
  const int s    = slot & 63;
  const int u    = (s < 32) ? (63 - s) : (s - 32);  // heavy+light pairing
  const int h = g & 15, b = g >> 4;
  const int qA = u * 32, qB = qA + 16;
  const int nchunk = u / 2 + 1;            // 64-key chunks

  const int RS = 3072;
  const u16* base = QKV + (size_t)b * 2048 * RS;
  const u16* Qb  = base + h * 64;
  const u16* Kb  = base + 1024 + h * 64;
  const u16* VTb = VT + (size_t)h * 64 * 4096 + (size_t)b * 2048;

  // Q frags (B-operand): lane holds Q[q+lq][d = 32*half + quad*8 + j]
  s8v qfA0 = *(const s8v*)&Qb[(size_t)(qA + lq) * RS + quad * 8];
  s8v qfA1 = *(const s8v*)&Qb[(size_t)(qA + lq) * RS + 32 + quad * 8];
  s8v qfB0 = *(const s8v*)&Qb[(size_t)(qB + lq) * RS + quad * 8];
  s8v qfB1 = *(const s8v*)&Qb[(size_t)(qB + lq) * RS + 32 + quad * 8];

  f4v zA[4] = {}, zB[4] = {};
  float mA = -3.0e38f, lA = 0.f, mB = -3.0e38f, lB = 0.f;

  s8v kf[8], vf[8];   // single buffers: K rows / V cols of the current chunk

#define LOADK(c_) do {                                                        \
    const int kk0_ = (c_) * 64;                                               \
    _Pragma("unroll")                                                         \
    for (int i_ = 0; i_ < 4; ++i_) {                                          \
      const u16* kr_ = &Kb[(size_t)(kk0_ + 16 * i_ + lq) * RS + quad * 8];    \
      kf[2 * i_]     = *(const s8v*)kr_;                                      \
      kf[2 * i_ + 1] = *(const s8v*)(kr_ + 32);                               \
    }                                                                         \
  } while (0)

#define LOADV(c_) do {                                                        \
    const int kk0_ = (c_) * 64;                                               \
    _Pragma("unroll")                                                         \
    for (int d_ = 0; d_ < 4; ++d_) {                                          \
      const u16* vr_ = &VTb[(size_t)(d_ * 16 + lq) * 4096 + kk0_ + quad * 8]; \
      vf[d_]     = *(const s8v*)vr_;                                          \
      vf[d_ + 4] = *(const s8v*)(vr_ + 32);                                   \
    }                                                                         \
  } while (0)

  // softmax of 64-key chunk c for one tile (swapped layout) + packed P write
  auto SMW = [&](int c, int qt0, float& mrow, float& lsum, f4v (&zacc)[4],
                 u16* sPt, f4v (&sc)[4]) {
    float sv[4][4];
    for (int i = 0; i < 4; ++i)
      for (int r = 0; r < 4; ++r) sv[i][r] = sc[i][r];
    if (c + 1 == nchunk) {              // only the last chunk crosses the diagonal
      const int kb = c * 64;
      for (int i = 0; i < 4; ++i)
        for (int r = 0; r < 4; ++r)
          if (kb + 16 * i + quad * 4 + r > qt0 + lq) sv[i][r] = -3.0e38f;
    }
    float lmax = sv[0][0];
    for (int i = 0; i < 4; ++i)
      for (int r = 0; r < 4; ++r) lmax = fmaxf(lmax, sv[i][r]);
    if (!__all(lmax <= mrow + 8.0f)) {  // defer-max, THR=8
      float t = lmax;
      t = fmaxf(t, __shfl_xor(t, 16, 64));
      t = fmaxf(t, __shfl_xor(t, 32, 64));
      float mnew = fmaxf(mrow, t);
      float al = __expf(mrow - mnew);
      mrow = mnew;
      lsum *= al;
      float alr[4];
      for (int r = 0; r < 4; ++r) alr[r] = __shfl(al, quad * 4 + r, 16);
      for (int dc = 0; dc < 4; ++dc)
        for (int r = 0; r < 4; ++r) zacc[dc][r] *= alr[r];
    }
    float acc = 0.f;
    float p[4][4];
    for (int i = 0; i < 4; ++i)
      for (int r = 0; r < 4; ++r) {
        p[i][r] = __expf(sv[i][r] - mrow);
        acc += p[i][r];
      }
    lsum += acc;
    for (int i = 0; i < 4; ++i) {
      uint2 w;
      w.x = pk2(p[i][0], p[i][1]);
      w.y = pk2(p[i][2], p[i][3]);
      *(uint2*)&sPt[lq * 72 + 16 * i + quad * 4] = w;
    }
  };

#define QK(aA_, aB_) do {                                                     \
    _Pragma("unroll")                                                         \
    for (int i_ = 0; i_ < 4; ++i_) {                                          \
      aA_[i_] = __builtin_amdgcn_mfma_f32_16x16x32_bf16(kf[2*i_],   qfA0, aA_[i_], 0, 0, 0); \
      aA_[i_] = __builtin_amdgcn_mfma_f32_16x16x32_bf16(kf[2*i_+1], qfA1, aA_[i_], 0, 0, 0); \
      aB_[i_] = __builtin_amdgcn_mfma_f32_16x16x32_bf16(kf[2*i_],   qfB0, aB_[i_], 0, 0, 0); \
      aB_[i_] = __builtin_amdgcn_mfma_f32_16x16x32_bf16(kf[2*i_+1], qfB1, aB_[i_], 0, 0, 0); \
    }                                                                         \
  } while (0)

  // PV from ping-pong buffer pb (P of the previous chunk) + current vf
  auto PV = [&](int pb) {
    s8v pA0 = *(const s8v*)&sP[0][pb][lq * 72 + quad * 8];
    s8v pA1 = *(const s8v*)&sP[0][pb][lq * 72 + 32 + quad * 8];
    s8v pB0 = *(const s8v*)&sP[1][pb][lq * 72 + quad * 8];
    s8v pB1 = *(const s8v*)&sP[1][pb][lq * 72 + 32 + quad * 8];
#pragma unroll
    for (int d_ = 0; d_ < 4; ++d_) {
      zA[d_] = __builtin_amdgcn_mfma_f32_16x16x32_bf16(pA0, vf[d_],     zA[d_], 0, 0, 0);
      zA[d_] = __builtin_amdgcn_mfma_f32_16x16x32_bf16(pA1, vf[d_ + 4], zA[d_], 0, 0, 0);
      zB[d_] = __builtin_amdgcn_mfma_f32_16x16x32_bf16(pB0, vf[d_],     zB[d_], 0, 0, 0);
      zB[d_] = __builtin_amdgcn_mfma_f32_16x16x32_bf16(pB1, vf[d_ + 4], zB[d_], 0, 0, 0);
    }
  };

  LOADK(0);
  { // chunk 0: QK + softmax + P write into buf 0 (PV deferred)
    f4v aA[4] = {}, aB[4] = {};
    __builtin_amdgcn_s_setprio(1);
    QK(aA, aB);
    __builtin_amdgcn_s_setprio(0);
    if (nchunk > 1) LOADK(1);
    LOADV(0);
    SMW(0, qA, mA, lA, zA, sP[0][0], aA);
    SMW(0, qB, mB, lB, zB, sP[1][0], aB);
    asm volatile("" ::: "memory");      // P(0) writes pinned before PV reads
  }

  for (int c = 1; c < nchunk; ++c) {
    f4v aA[4] = {}, aB[4] = {};
    __builtin_amdgcn_s_setprio(1);
    QK(aA, aB);                         // kf = K(c)
    PV((c + 1) & 1);                    // reads P(c-1) + vf = V(c-1)
    __builtin_amdgcn_s_setprio(0);
    asm volatile("" ::: "memory");      // PV reads pinned before SMW writes
    if (c + 1 < nchunk) LOADK(c + 1);   // safe: QK consumed kf at issue
    LOADV(c);                           // safe: PV consumed vf at issue
    SMW(c, qA, mA, lA, zA, sP[0][c & 1], aA);
    SMW(c, qB, mB, lB, zB, sP[1][c & 1], aB);
    asm volatile("" ::: "memory");      // P(c) writes pinned before next PV
  }

  { // drain: PV(nchunk-1) from the last-written buffer
    __builtin_amdgcn_s_setprio(1);
    PV((nchunk - 1) & 1);
    __builtin_amdgcn_s_setprio(0);
  }
#undef QK
#undef LOADK
#undef LOADV

  // one-time sum reduction across the 4 quad-lanes of each row
  lA += __shfl_xor(lA, 16, 64); lA += __shfl_xor(lA, 32, 64);
  lB += __shfl_xor(lB, 16, 64); lB += __shfl_xor(lB, 32, 64);
  float invA[4], invB[4];
  for (int r = 0; r < 4; ++r) {
    invA[r] = 1.0f / __shfl(lA, quad * 4 + r, 16);
    invB[r] = 1.0f / __shfl(lB, quad * 4 + r, 16);
  }
  for (int dc = 0; dc < 4; ++dc)
    for (int r = 0; r < 4; ++r) {
      size_t rowA = (size_t)b * 2048 + qA + quad * 4 + r;
      size_t rowB = (size_t)b * 2048 + qB + quad * 4 + r;
      Z[rowA * 1024 + h * 64 + dc * 16 + lq] = f2b(zA[dc][r] * invA[r]);
      Z[rowB * 1024 + h * 64 + dc * 16 + lq] = f2b(zB[dc][r] * invB[r]);
    }
}

// ---------------------------------------------------------------------------
// Launch
// ---------------------------------------------------------------------------
extern "C" void kernel_launch(void* const* d_in, const int* in_sizes, int n_in,
                              void* d_out, int out_size, void* d_ws, size_t ws_size,
                              hipStream_t stream) {
  const float* x  = (const float*)d_in[0];
  const float* WQ = (const float*)d_in[1];
  const float* bQ = (const float*)d_in[2];
  const float* WK = (const float*)d_in[3];
  const float* bK = (const float*)d_in[4];
  const float* WV = (const float*)d_in[5];
  const float* WO = (const float*)d_in[6];
  const float* bV = (const float*)d_in[7];
  const float* bO = (const float*)d_in[8];
  float* out = (float*)d_out;

  uint8_t* ws = (uint8_t*)d_ws;
  u16*   xb    = (u16*)(ws);                       //  8 MB  [4096][1024] bf16 x
  u16*   WTqkv = (u16*)(ws + 8388608);             //  6 MB
  u16*   WOT   = (u16*)(ws + 14680064);            //  2 MB
  u16*   QKV   = (u16*)(ws + 16777216);            // 24 MB (V third unused)
  u16*   Zb    = (u16*)(ws + 41943040);            //  8 MB
  float* bqkv  = (float*)(ws + 50331648);          // 12 KB
  float* bsum  = (float*)(ws + 50343936);          //  4 KB
  u16*   VTv   = (u16*)(ws + 50348032);            //  8 MB V^T (own region)

  // fused prep: conv_x + 3x convT_w + convT_wo + conv_bias
  prep<<<5136, 256, 0, stream>>>(x, xb, WQ, WK, WV, WO, WTqkv, WOT,
                                 bQ, bK, bV, bO, bqkv, bsum);
  // QKV projection (Q cols pre-scaled by 0.125), fused V-transpose epilogue:
  // 128x128 tile, BK=32, 768 blocks = exactly 3/CU
  gemm_bt<false, 128, 128, 256, true, 32><<<dim3(24, 32), 256, 0, stream>>>(
      xb, WTqkv, bqkv, (void*)QKV, VTv, 3072, 1024, 1024);
  // attention: round-13 proven config, 2048 one-wave blocks
  attn_fwd<<<dim3(2048, 1, 1), 64, 0, stream>>>(QKV, VTv, Zb);
  // output projection: 128x64 tile, BK=64 (2 half-stages), 512 blocks = 2/CU
  gemm_bt<true, 128, 64, 256, false, 64><<<dim3(16, 32), 256, 0, stream>>>(
      Zb, WOT, bsum, (void*)out, nullptr, 1024, 1024, 0);
}